// Round 1
// baseline (5851.432 us; speedup 1.0000x reference)
//
#include <hip/hip_runtime.h>

#define Bb 32
#define Tt 2048
#define Dd 256
#define Hh 256
#define G3 768  // 3*H

typedef _Float16 h2_t __attribute__((ext_vector_type(2)));
union H2U { unsigned u; h2_t h; };

__device__ __forceinline__ float fdot2f(h2_t a, h2_t b, float c) {
#if __has_builtin(__builtin_amdgcn_fdot2)
    return __builtin_amdgcn_fdot2(a, b, c, false);
#else
    return c + (float)a[0] * (float)b[0] + (float)a[1] * (float)b[1];
#endif
}

__device__ __forceinline__ float frcpf(float x) {
#if __has_builtin(__builtin_amdgcn_rcpf)
    return __builtin_amdgcn_rcpf(x);
#else
    return 1.0f / x;
#endif
}

__device__ __forceinline__ float sigmoidf_(float s) {
    return frcpf(1.0f + __expf(-s));
}
// tanh(u) = 1 - 2/(exp(2u)+1); saturates correctly at +-inf
__device__ __forceinline__ float tanhf_(float u) {
    float e = __expf(2.0f * u);
    return 1.0f - 2.0f * frcpf(e + 1.0f);
}

// ---------------------------------------------------------------------------
// Phase 1: x_proj[m][n] = sum_k x[m][k] * Wx[k][n] + b[n], stored f16 in ws.
// m in [0,65536), n in [0,768), k in [0,256).
// Row-per-thread; x row lives in 128 f16x2 registers; W_x staged to LDS in
// 48-column chunks, read as 64-lane broadcasts (conflict-free).
// ---------------------------------------------------------------------------
#define P1_THREADS 128
#define P1_NCH 48

__global__ __launch_bounds__(P1_THREADS, 2)
void xproj_kernel(const float* __restrict__ x, const float* __restrict__ Wx,
                  const float* __restrict__ bias, _Float16* __restrict__ xp)
{
    // [n][kc] f16x2-packed W_x chunk; 132 stride: 16B-aligned rows + bank spread
    __shared__ unsigned wxt[P1_NCH][132];
    const int tid = threadIdx.x;
    const size_t row = (size_t)blockIdx.x * P1_THREADS + tid;

    // x row -> registers (f16x2 packed)
    unsigned xreg[128];
    {
        const float4* xrow = reinterpret_cast<const float4*>(x + row * Dd);
#pragma unroll
        for (int k4 = 0; k4 < 64; ++k4) {
            float4 v = xrow[k4];
            H2U a, b;
            a.h[0] = (_Float16)v.x; a.h[1] = (_Float16)v.y;
            b.h[0] = (_Float16)v.z; b.h[1] = (_Float16)v.w;
            xreg[2 * k4]     = a.u;
            xreg[2 * k4 + 1] = b.u;
        }
    }

    for (int c = 0; c < 16; ++c) {
        const int nb = c * P1_NCH;
        __syncthreads();  // protect wxt overwrite vs previous chunk's readers
        // stage Wx[:, nb..nb+48) as f16x2, transposed to [n][kc]
        for (int i = tid; i < P1_NCH * 128; i += P1_THREADS) {
            int kc = i / P1_NCH;
            int n  = i - kc * P1_NCH;
            float f0 = Wx[(size_t)(2 * kc)     * G3 + nb + n];
            float f1 = Wx[(size_t)(2 * kc + 1) * G3 + nb + n];
            H2U u; u.h[0] = (_Float16)f0; u.h[1] = (_Float16)f1;
            wxt[n][kc] = u.u;
        }
        __syncthreads();

        for (int ng = 0; ng < 6; ++ng) {
            _Float16 o8[8];
#pragma unroll
            for (int n8 = 0; n8 < 8; ++n8) {
                const int n = ng * 8 + n8;
                float a0 = 0.f, a1 = 0.f, a2 = 0.f, a3 = 0.f;
                const uint4* wrow = reinterpret_cast<const uint4*>(&wxt[n][0]);
#pragma unroll
                for (int kq = 0; kq < 32; ++kq) {
                    uint4 wv = wrow[kq];  // 64-lane broadcast, conflict-free
                    H2U w0, w1, w2, w3, x0, x1, x2, x3;
                    w0.u = wv.x; w1.u = wv.y; w2.u = wv.z; w3.u = wv.w;
                    x0.u = xreg[kq * 4 + 0]; x1.u = xreg[kq * 4 + 1];
                    x2.u = xreg[kq * 4 + 2]; x3.u = xreg[kq * 4 + 3];
                    a0 = fdot2f(w0.h, x0.h, a0);   // 4 accumulators break the
                    a1 = fdot2f(w1.h, x1.h, a1);   // dependency chain
                    a2 = fdot2f(w2.h, x2.h, a2);
                    a3 = fdot2f(w3.h, x3.h, a3);
                }
                float s = ((a0 + a1) + (a2 + a3)) + bias[nb + n];
                o8[n8] = (_Float16)s;
            }
            uint4 ov;
            H2U p0, p1, p2, p3;
            p0.h[0] = o8[0]; p0.h[1] = o8[1];
            p1.h[0] = o8[2]; p1.h[1] = o8[3];
            p2.h[0] = o8[4]; p2.h[1] = o8[5];
            p3.h[0] = o8[6]; p3.h[1] = o8[7];
            ov.x = p0.u; ov.y = p1.u; ov.z = p2.u; ov.w = p3.u;
            *reinterpret_cast<uint4*>(xp + row * G3 + nb + ng * 8) = ov;
        }
    }
}

// ---------------------------------------------------------------------------
// Phase 2: sequential GRU scan. One block per batch element (32 blocks).
// Thread j owns W_h columns {j, j+256, j+512} in 384 f16x2 VGPRs (register-
// resident weights; no per-step W_h memory traffic). h is double-buffered in
// LDS (f16) and broadcast-read; the fp32 carry h[j] stays in a register so
// f16 rounding does not accumulate through the z*h term.
// ---------------------------------------------------------------------------
__global__ __launch_bounds__(256, 1)
void gru_scan_kernel(const _Float16* __restrict__ xp, const float* __restrict__ Wh,
                     float* __restrict__ y)
{
    __shared__ unsigned hbuf[2][128];  // 2 x 256 f16
    const int b = blockIdx.x;
    const int j = threadIdx.x;

    // Load this thread's 3 weight columns, packed f16x2 along k.
    unsigned wz[128], wr[128], wn[128];
#pragma unroll
    for (int kc = 0; kc < 128; ++kc) {
        const float* r0 = Wh + (size_t)(2 * kc)     * G3;
        const float* r1 = Wh + (size_t)(2 * kc + 1) * G3;
        H2U uz, ur, un;
        uz.h[0] = (_Float16)r0[j];          uz.h[1] = (_Float16)r1[j];
        ur.h[0] = (_Float16)r0[j + Hh];     ur.h[1] = (_Float16)r1[j + Hh];
        un.h[0] = (_Float16)r0[j + 2 * Hh]; un.h[1] = (_Float16)r1[j + 2 * Hh];
        wz[kc] = uz.u; wr[kc] = ur.u; wn[kc] = un.u;
    }

    if (j < 128) hbuf[0][j] = 0u;  // h0 = 0
    float hprev = 0.0f;

    const _Float16* xpb = xp + (size_t)b * Tt * G3;
    float xz = (float)xpb[j];
    float xr = (float)xpb[j + Hh];
    float xn = (float)xpb[j + 2 * Hh];

    float* yb = y + (size_t)b * Tt * Hh + j;

    __syncthreads();

    int p = 0;
    for (int t = 0; t < Tt; ++t) {
        // prefetch next step's x_proj triple (consumed next iteration)
        const _Float16* xpn = xpb + (size_t)(t + 1 < Tt ? t + 1 : t) * G3;
        float nxz = (float)xpn[j];
        float nxr = (float)xpn[j + Hh];
        float nxn = (float)xpn[j + 2 * Hh];

        // h @ Wh for this thread's 3 columns; 6 accumulators, gate-rotated
        // issue order keeps same-acc dot2s 6 slots apart (no dep stalls).
        float az0 = 0.f, az1 = 0.f, ar0 = 0.f, ar1 = 0.f, an0 = 0.f, an1 = 0.f;
        const uint4* hb = reinterpret_cast<const uint4*>(&hbuf[p][0]);
#pragma unroll
        for (int q = 0; q < 32; ++q) {
            uint4 hv = hb[q];  // 64-lane broadcast read
            H2U h0, h1, h2, h3;
            h0.u = hv.x; h1.u = hv.y; h2.u = hv.z; h3.u = hv.w;
            H2U w;
            w.u = wz[q * 4 + 0]; az0 = fdot2f(w.h, h0.h, az0);
            w.u = wr[q * 4 + 0]; ar0 = fdot2f(w.h, h0.h, ar0);
            w.u = wn[q * 4 + 0]; an0 = fdot2f(w.h, h0.h, an0);
            w.u = wz[q * 4 + 1]; az1 = fdot2f(w.h, h1.h, az1);
            w.u = wr[q * 4 + 1]; ar1 = fdot2f(w.h, h1.h, ar1);
            w.u = wn[q * 4 + 1]; an1 = fdot2f(w.h, h1.h, an1);
            w.u = wz[q * 4 + 2]; az0 = fdot2f(w.h, h2.h, az0);
            w.u = wr[q * 4 + 2]; ar0 = fdot2f(w.h, h2.h, ar0);
            w.u = wn[q * 4 + 2]; an0 = fdot2f(w.h, h2.h, an0);
            w.u = wz[q * 4 + 3]; az1 = fdot2f(w.h, h3.h, az1);
            w.u = wr[q * 4 + 3]; ar1 = fdot2f(w.h, h3.h, ar1);
            w.u = wn[q * 4 + 3]; an1 = fdot2f(w.h, h3.h, an1);
        }
        float hz = az0 + az1, hr = ar0 + ar1, hn = an0 + an1;

        float zg = sigmoidf_(xz + hz);
        float rg = sigmoidf_(xr + hr);
        float ng = tanhf_(xn + rg * hn);
        float hnew = zg * hprev + (1.0f - zg) * ng;

        yb[(size_t)t * Hh] = hnew;  // fp32 output, coalesced

        reinterpret_cast<_Float16*>(&hbuf[p ^ 1][0])[j] = (_Float16)hnew;
        __syncthreads();

        hprev = hnew;
        p ^= 1;
        xz = nxz; xr = nxr; xn = nxn;
    }
}

extern "C" void kernel_launch(void* const* d_in, const int* in_sizes, int n_in,
                              void* d_out, int out_size, void* d_ws, size_t ws_size,
                              hipStream_t stream)
{
    (void)in_sizes; (void)n_in; (void)out_size; (void)ws_size;
    const float* x    = (const float*)d_in[0];
    const float* Wx   = (const float*)d_in[1];
    const float* Wh   = (const float*)d_in[2];
    const float* bias = (const float*)d_in[3];
    float* y = (float*)d_out;
    _Float16* xp = (_Float16*)d_ws;  // 65536 x 768 f16 = 96 MB

    xproj_kernel<<<dim3((Bb * Tt) / P1_THREADS), dim3(P1_THREADS), 0, stream>>>(x, Wx, bias, xp);
    gru_scan_kernel<<<dim3(Bb), dim3(256), 0, stream>>>(xp, Wh, y);
}

// Round 2
// 3407.795 us; speedup vs baseline: 1.7171x; 1.7171x over previous
//
#include <hip/hip_runtime.h>

#define Bb 32
#define Tt 2048
#define Dd 256
#define Hh 256
#define G3 768  // 3*H

typedef _Float16 h2_t __attribute__((ext_vector_type(2)));
typedef _Float16 f16x8 __attribute__((ext_vector_type(8)));
typedef float f32x4 __attribute__((ext_vector_type(4)));
union H2U { unsigned u; h2_t h; };
union V16 { uint4 u; f16x8 f; };

__device__ __forceinline__ float fdot2f(unsigned a, unsigned b, float c) {
#if __has_builtin(__builtin_amdgcn_fdot2)
    H2U ua, ub; ua.u = a; ub.u = b;
    return __builtin_amdgcn_fdot2(ua.h, ub.h, c, false);
#else
    H2U ua, ub; ua.u = a; ub.u = b;
    return c + (float)ua.h[0] * (float)ub.h[0] + (float)ua.h[1] * (float)ub.h[1];
#endif
}

__device__ __forceinline__ float frcpf(float x) {
#if __has_builtin(__builtin_amdgcn_rcpf)
    return __builtin_amdgcn_rcpf(x);
#else
    return 1.0f / x;
#endif
}
__device__ __forceinline__ float sigmoidf_(float s) { return frcpf(1.0f + __expf(-s)); }
__device__ __forceinline__ float tanhf_(float u) {
    float e = __expf(2.0f * u);
    return 1.0f - 2.0f * frcpf(e + 1.0f);
}

// butterfly-sum over 8-lane groups, pure VALU (DPP), no LDS pipe
__device__ __forceinline__ float dppadd3(float v) {
    v += __int_as_float(__builtin_amdgcn_update_dpp(0, __float_as_int(v), 0xB1, 0xF, 0xF, true));  // xor 1
    v += __int_as_float(__builtin_amdgcn_update_dpp(0, __float_as_int(v), 0x4E, 0xF, 0xF, true));  // xor 2
    v += __int_as_float(__builtin_amdgcn_update_dpp(0, __float_as_int(v), 0x141, 0xF, 0xF, true)); // half_mirror: pairs l<->7-l
    return v;
}
__device__ __forceinline__ float sel4(const float a[4], int qq) {
    float t0 = (qq & 1) ? a[1] : a[0];
    float t1 = (qq & 1) ? a[3] : a[2];
    return (qq & 2) ? t1 : t0;
}

// ---------------------------------------------------------------------------
// k0: x fp32 -> f16 (into d_out scratch region)
// ---------------------------------------------------------------------------
__global__ void cvt_x_kernel(const float* __restrict__ x, _Float16* __restrict__ xo) {
    const size_t i = ((size_t)blockIdx.x * 256 + threadIdx.x) * 4;
    float4 v = *reinterpret_cast<const float4*>(x + i);
    H2U a, b;
    a.h[0] = (_Float16)v.x; a.h[1] = (_Float16)v.y;
    b.h[0] = (_Float16)v.z; b.h[1] = (_Float16)v.w;
    uint2 o; o.x = a.u; o.y = b.u;
    *reinterpret_cast<uint2*>(xo + i) = o;
}

// ---------------------------------------------------------------------------
// k1: WxT[n][k] f16 from Wx[k][n] fp32  (768 x 256)
// ---------------------------------------------------------------------------
__global__ void wxt_kernel(const float* __restrict__ Wx, _Float16* __restrict__ wxt) {
    const int o = blockIdx.x * 256 + threadIdx.x;  // o = n*128 + kp, kp packs k pair
    const int n = o >> 7, kp = o & 127;
    float f0 = Wx[(size_t)(2 * kp) * G3 + n];
    float f1 = Wx[(size_t)(2 * kp + 1) * G3 + n];
    H2U u; u.h[0] = (_Float16)f0; u.h[1] = (_Float16)f1;
    reinterpret_cast<unsigned*>(wxt)[o] = u.u;
}

// ---------------------------------------------------------------------------
// k2: xp = A(65536x256,f16) @ WxT^T + bias, f16 out. MFMA 16x16x32_f16.
// Tile BM=128 x BN=64, whole K resident in LDS, 4 waves (2m x 2n),
// wave = 64 rows x 32 cols (acc 4x2 tiles). Rows padded to 264 f16 so the
// 16-row fragment reads spread uniformly over banks (8 lanes/bank-quad = the
// b128 minimum).
// ---------------------------------------------------------------------------
__global__ __launch_bounds__(256)
void gemm_xp_kernel(const _Float16* __restrict__ A, const _Float16* __restrict__ Bm,
                    const float* __restrict__ bias, _Float16* __restrict__ xp) {
    __shared__ _Float16 As[128][264];
    __shared__ _Float16 Bs[64][264];
    const int tid = threadIdx.x;
    const int m0 = (blockIdx.x / 12) * 128;
    const int n0 = (blockIdx.x % 12) * 64;

#pragma unroll
    for (int it = 0; it < 16; ++it) {           // A tile: 128 rows x 256 k
        int c = tid + it * 256, row = c >> 5, col = c & 31;
        uint4 v = *reinterpret_cast<const uint4*>(A + (size_t)(m0 + row) * 256 + col * 8);
        *reinterpret_cast<uint4*>(&As[row][col * 8]) = v;
    }
#pragma unroll
    for (int it = 0; it < 8; ++it) {            // B tile: 64 n-rows x 256 k
        int c = tid + it * 256, row = c >> 5, col = c & 31;
        uint4 v = *reinterpret_cast<const uint4*>(Bm + (size_t)(n0 + row) * 256 + col * 8);
        *reinterpret_cast<uint4*>(&Bs[row][col * 8]) = v;
    }
    __syncthreads();

    const int wave = tid >> 6, lane = tid & 63;
    const int wr = wave >> 1, wc = wave & 1;
    const int r16 = lane & 15, kg = lane >> 4;

    f32x4 acc[4][2];
#pragma unroll
    for (int mi = 0; mi < 4; ++mi)
#pragma unroll
        for (int ni = 0; ni < 2; ++ni) acc[mi][ni] = (f32x4){0.f, 0.f, 0.f, 0.f};

    float bv[2];
#pragma unroll
    for (int ni = 0; ni < 2; ++ni) bv[ni] = bias[n0 + wc * 32 + ni * 16 + r16];

#pragma unroll
    for (int kk = 0; kk < 8; ++kk) {
        f16x8 a[4], b2[2];
#pragma unroll
        for (int mi = 0; mi < 4; ++mi) {
            V16 t; t.u = *reinterpret_cast<const uint4*>(&As[wr * 64 + mi * 16 + r16][kk * 32 + kg * 8]);
            a[mi] = t.f;
        }
#pragma unroll
        for (int ni = 0; ni < 2; ++ni) {
            V16 t; t.u = *reinterpret_cast<const uint4*>(&Bs[wc * 32 + ni * 16 + r16][kk * 32 + kg * 8]);
            b2[ni] = t.f;
        }
#pragma unroll
        for (int mi = 0; mi < 4; ++mi)
#pragma unroll
            for (int ni = 0; ni < 2; ++ni)
                acc[mi][ni] = __builtin_amdgcn_mfma_f32_16x16x32_f16(a[mi], b2[ni], acc[mi][ni], 0, 0, 0);
    }

    // D layout: col = lane&15, row = 4*(lane>>4) + r   [m89-verified, shape-determined]
#pragma unroll
    for (int mi = 0; mi < 4; ++mi)
#pragma unroll
        for (int ni = 0; ni < 2; ++ni)
#pragma unroll
            for (int r = 0; r < 4; ++r) {
                int row = m0 + wr * 64 + mi * 16 + kg * 4 + r;
                int col = n0 + wc * 32 + ni * 16 + r16;
                xp[(size_t)row * G3 + col] = (_Float16)(acc[mi][ni][r] + bv[ni]);
            }
}

// ---------------------------------------------------------------------------
// k3: GRU scan. 32 blocks x 512 threads (8 waves). Thread (u=tid>>3, q=tid&7)
// owns gate-cols {4u+d + 256g : d<4, g<3} over k in [32q, 32q+32):
// weights = 192 VGPRs (fits the 256 architectural VGPRs; v_dot2 cannot read
// AGPRs, which is what spilled last round's 384-reg version).
// h lives in LDS as 8 k-slices of 16 u32, padded to 20 (conflict-free b128).
// Cross-q reduction via DPP butterflies on the VALU. Raw s_barrier with
// lgkmcnt(0) only -- no vmcnt drain, so y-stores/xp-loads stay in flight.
// ---------------------------------------------------------------------------
#define GRU_STEP(PR, PW, T)                                                           \
  {                                                                                   \
    float xg0 = 0.f, xg1 = 0.f, xg2 = 0.f;                                            \
    if (q < 4) {                                                                      \
      const _Float16* xt = xpb + (size_t)(T) * G3 + jq;                               \
      xg0 = (float)xt[0]; xg1 = (float)xt[Hh]; xg2 = (float)xt[2 * Hh];               \
    }                                                                                 \
    float acc[3][4];                                                                  \
    _Pragma("unroll") for (int g = 0; g < 3; ++g)                                     \
      _Pragma("unroll") for (int d = 0; d < 4; ++d) acc[g][d] = 0.f;                  \
    const uint4* hq = reinterpret_cast<const uint4*>(&hb[PR][q * 20]);                \
    _Pragma("unroll") for (int i4 = 0; i4 < 4; ++i4) {                                \
      uint4 hv = hq[i4];                                                              \
      unsigned hh[4] = {hv.x, hv.y, hv.z, hv.w};                                      \
      _Pragma("unroll") for (int ii = 0; ii < 4; ++ii) {                              \
        _Pragma("unroll") for (int g = 0; g < 3; ++g)                                 \
          _Pragma("unroll") for (int d = 0; d < 4; ++d)                               \
            acc[g][d] = fdot2f(w[g][d][i4 * 4 + ii], hh[ii], acc[g][d]);              \
      }                                                                               \
    }                                                                                 \
    _Pragma("unroll") for (int g = 0; g < 3; ++g)                                     \
      _Pragma("unroll") for (int d = 0; d < 4; ++d) acc[g][d] = dppadd3(acc[g][d]);   \
    if (q < 4) {                                                                      \
      float hz = sel4(acc[0], q), hr = sel4(acc[1], q), hn = sel4(acc[2], q);         \
      float zg = sigmoidf_(xg0 + hz);                                                 \
      float rg = sigmoidf_(xg1 + hr);                                                 \
      float ng = tanhf_(xg2 + rg * hn);                                               \
      float hnew = zg * hprev + (1.0f - zg) * ng;                                     \
      hprev = hnew;                                                                   \
      H2U hc; hc.h[0] = (_Float16)hnew; hc.h[1] = (_Float16)0.f;                      \
      unsigned pu = (unsigned)__builtin_amdgcn_update_dpp(0, (int)hc.u, 0xB1, 0xF, 0xF, true); \
      int pf = __builtin_amdgcn_update_dpp(0, __float_as_int(hnew), 0xB1, 0xF, 0xF, true);      \
      if ((q & 1) == 0) {                                                             \
        unsigned hpack = (hc.u & 0xFFFFu) | (pu << 16);                               \
        const int iu = 2 * u + (q >> 1);                                              \
        hb[PW][(iu >> 4) * 20 + (iu & 15)] = hpack;                                   \
        float2 yv; yv.x = hnew; yv.y = __int_as_float(pf);                            \
        *reinterpret_cast<float2*>(yb + (size_t)(T) * Hh + 4 * u + q) = yv;           \
      }                                                                               \
    }                                                                                 \
    __builtin_amdgcn_sched_barrier(0);                                                \
    asm volatile("s_waitcnt lgkmcnt(0)" ::: "memory");                                \
    __builtin_amdgcn_s_barrier();                                                     \
    __builtin_amdgcn_sched_barrier(0);                                                \
  }

__global__ __launch_bounds__(512, 2)
void gru_scan_kernel(const _Float16* __restrict__ xp, const float* __restrict__ Wh,
                     float* __restrict__ y) {
    __shared__ unsigned hb[2][160];  // [buf][slice q][16 u32 + 4 pad]
    const int tid = threadIdx.x;
    const int b = blockIdx.x;
    const int q = tid & 7;
    const int u = tid >> 3;          // [0,64)
    const int jq = 4 * u + q;        // this lane's j (valid when q<4)

    unsigned w[3][4][16];            // [gate][d][k-pair]
#pragma unroll
    for (int g = 0; g < 3; ++g)
#pragma unroll
        for (int kp = 0; kp < 16; ++kp) {
            const int k = 32 * q + 2 * kp;
            const float* r0 = Wh + (size_t)k * G3 + g * Hh + 4 * u;
            float4 va = *reinterpret_cast<const float4*>(r0);
            float4 vb = *reinterpret_cast<const float4*>(r0 + G3);
            H2U p0, p1, p2, p3;
            p0.h[0] = (_Float16)va.x; p0.h[1] = (_Float16)vb.x;
            p1.h[0] = (_Float16)va.y; p1.h[1] = (_Float16)vb.y;
            p2.h[0] = (_Float16)va.z; p2.h[1] = (_Float16)vb.z;
            p3.h[0] = (_Float16)va.w; p3.h[1] = (_Float16)vb.w;
            w[g][0][kp] = p0.u; w[g][1][kp] = p1.u;
            w[g][2][kp] = p2.u; w[g][3][kp] = p3.u;
        }

    if (tid < 160) hb[0][tid] = 0u;  // h0 = 0 (buf 0)
    float hprev = 0.0f;

    const _Float16* xpb = xp + (size_t)b * Tt * G3;
    float* yb = y + (size_t)b * Tt * Hh;

    __syncthreads();  // one-time full barrier (also drains weight loads)

#pragma unroll 1
    for (int t = 0; t < Tt; t += 2) {
        GRU_STEP(0, 1, t);
        GRU_STEP(1, 0, t + 1);
    }
}

extern "C" void kernel_launch(void* const* d_in, const int* in_sizes, int n_in,
                              void* d_out, int out_size, void* d_ws, size_t ws_size,
                              hipStream_t stream) {
    (void)in_sizes; (void)n_in; (void)out_size; (void)ws_size;
    const float* x    = (const float*)d_in[0];
    const float* Wx   = (const float*)d_in[1];
    const float* Wh   = (const float*)d_in[2];
    const float* bias = (const float*)d_in[3];
    float* y = (float*)d_out;

    _Float16* xp   = (_Float16*)d_ws;                                // 96 MB
    _Float16* xf16 = (_Float16*)d_out;                               // 33.5 MB scratch in d_out
    _Float16* wxt  = (_Float16*)((char*)d_out + (size_t)33554432);   // 384 KB, after xf16

    cvt_x_kernel<<<dim3(16384), dim3(256), 0, stream>>>(x, xf16);
    wxt_kernel<<<dim3(384), dim3(256), 0, stream>>>(Wx, wxt);
    gemm_xp_kernel<<<dim3(6144), dim3(256), 0, stream>>>(xf16, wxt, bias, xp);
    // scan reads only ws, writes all of d_out (overwriting the scratch regions)
    gru_scan_kernel<<<dim3(Bb), dim3(512), 0, stream>>>(xp, Wh, y);
}

// Round 3
// 2201.114 us; speedup vs baseline: 2.6584x; 1.5482x over previous
//
#include <hip/hip_runtime.h>

#define Bb 32
#define Tt 2048
#define Dd 256
#define Hh 256
#define G3 768  // 3*H

typedef _Float16 f16x8 __attribute__((ext_vector_type(8)));
typedef float f32x4 __attribute__((ext_vector_type(4)));
union H2U { unsigned u; _Float16 h[2]; };
union V16 { uint4 u; f16x8 f; };

__device__ __forceinline__ float frcpf(float x) {
#if __has_builtin(__builtin_amdgcn_rcpf)
    return __builtin_amdgcn_rcpf(x);
#else
    return 1.0f / x;
#endif
}
__device__ __forceinline__ float sigmoidf_(float s) { return frcpf(1.0f + __expf(-s)); }
__device__ __forceinline__ float tanhf_(float u) {
    float e = __expf(2.0f * u);
    return 1.0f - 2.0f * frcpf(e + 1.0f);
}

// ---------------------------------------------------------------------------
// k0: x fp32 -> f16 (into d_out scratch region)
// ---------------------------------------------------------------------------
__global__ void cvt_x_kernel(const float* __restrict__ x, _Float16* __restrict__ xo) {
    const size_t i = ((size_t)blockIdx.x * 256 + threadIdx.x) * 4;
    float4 v = *reinterpret_cast<const float4*>(x + i);
    H2U a, b;
    a.h[0] = (_Float16)v.x; a.h[1] = (_Float16)v.y;
    b.h[0] = (_Float16)v.z; b.h[1] = (_Float16)v.w;
    uint2 o; o.x = a.u; o.y = b.u;
    *reinterpret_cast<uint2*>(xo + i) = o;
}

// ---------------------------------------------------------------------------
// k1: WxT[n][k] f16 from Wx[k][n] fp32  (768 x 256)
// ---------------------------------------------------------------------------
__global__ void wxt_kernel(const float* __restrict__ Wx, _Float16* __restrict__ wxt) {
    const int o = blockIdx.x * 256 + threadIdx.x;  // o = n*128 + kp
    const int n = o >> 7, kp = o & 127;
    float f0 = Wx[(size_t)(2 * kp) * G3 + n];
    float f1 = Wx[(size_t)(2 * kp + 1) * G3 + n];
    H2U u; u.h[0] = (_Float16)f0; u.h[1] = (_Float16)f1;
    reinterpret_cast<unsigned*>(wxt)[o] = u.u;
}

// ---------------------------------------------------------------------------
// k2: xp = A(65536x256,f16) @ WxT^T + bias, f16 out. MFMA 16x16x32_f16.
// (unchanged from round 2 -- ref-checked, ~80 us for k0..k2 combined)
// ---------------------------------------------------------------------------
__global__ __launch_bounds__(256)
void gemm_xp_kernel(const _Float16* __restrict__ A, const _Float16* __restrict__ Bm,
                    const float* __restrict__ bias, _Float16* __restrict__ xp) {
    __shared__ _Float16 As[128][264];
    __shared__ _Float16 Bs[64][264];
    const int tid = threadIdx.x;
    const int m0 = (blockIdx.x / 12) * 128;
    const int n0 = (blockIdx.x % 12) * 64;

#pragma unroll
    for (int it = 0; it < 16; ++it) {
        int c = tid + it * 256, row = c >> 5, col = c & 31;
        uint4 v = *reinterpret_cast<const uint4*>(A + (size_t)(m0 + row) * 256 + col * 8);
        *reinterpret_cast<uint4*>(&As[row][col * 8]) = v;
    }
#pragma unroll
    for (int it = 0; it < 8; ++it) {
        int c = tid + it * 256, row = c >> 5, col = c & 31;
        uint4 v = *reinterpret_cast<const uint4*>(Bm + (size_t)(n0 + row) * 256 + col * 8);
        *reinterpret_cast<uint4*>(&Bs[row][col * 8]) = v;
    }
    __syncthreads();

    const int wave = tid >> 6, lane = tid & 63;
    const int wr = wave >> 1, wc = wave & 1;
    const int r16 = lane & 15, kg = lane >> 4;

    f32x4 acc[4][2];
#pragma unroll
    for (int mi = 0; mi < 4; ++mi)
#pragma unroll
        for (int ni = 0; ni < 2; ++ni) acc[mi][ni] = (f32x4){0.f, 0.f, 0.f, 0.f};

    float bv[2];
#pragma unroll
    for (int ni = 0; ni < 2; ++ni) bv[ni] = bias[n0 + wc * 32 + ni * 16 + r16];

#pragma unroll
    for (int kk = 0; kk < 8; ++kk) {
        f16x8 a[4], b2[2];
#pragma unroll
        for (int mi = 0; mi < 4; ++mi) {
            V16 t; t.u = *reinterpret_cast<const uint4*>(&As[wr * 64 + mi * 16 + r16][kk * 32 + kg * 8]);
            a[mi] = t.f;
        }
#pragma unroll
        for (int ni = 0; ni < 2; ++ni) {
            V16 t; t.u = *reinterpret_cast<const uint4*>(&Bs[wc * 32 + ni * 16 + r16][kk * 32 + kg * 8]);
            b2[ni] = t.f;
        }
#pragma unroll
        for (int mi = 0; mi < 4; ++mi)
#pragma unroll
            for (int ni = 0; ni < 2; ++ni)
                acc[mi][ni] = __builtin_amdgcn_mfma_f32_16x16x32_f16(a[mi], b2[ni], acc[mi][ni], 0, 0, 0);
    }

#pragma unroll
    for (int mi = 0; mi < 4; ++mi)
#pragma unroll
        for (int ni = 0; ni < 2; ++ni)
#pragma unroll
            for (int r = 0; r < 4; ++r) {
                int row = m0 + wr * 64 + mi * 16 + kg * 4 + r;
                int col = n0 + wc * 32 + ni * 16 + r16;
                xp[(size_t)row * G3 + col] = (_Float16)(acc[mi][ni][r] + bv[ni]);
            }
}

// ---------------------------------------------------------------------------
// k3: GRU scan via MFMA. 32 blocks (1/batch) x 512 threads (8 waves).
// Per step: h(1x256) @ Wh(256x768) done as 384 mfma_16x16x32_f16 with h
// BROADCAST into all 16 A-rows (every lane reads the same h k-chunk from LDS,
// so all D rows are identical and reg[0] holds the result -- no extraction).
// Wave w owns cols 32w..32w+31 for all 3 gates = 6 N-tiles x 8 K-steps.
// Weights: K-steps 0..5 register-resident (36 frags = 144 VGPR), K-steps 6..7
// streamed from LDS f16 (stride 40 f16 = 80 B: 16B-aligned, uniform 2-way
// banks = free). All arrays statically indexed; NOTHING passed by pointer
// (round-2 lesson: sel4's array param escaped -> alloca promoted to LDS).
// One lgkmcnt-only barrier per step (h double-buffered; vmcnt never drained
// in the loop so xp prefetch / y stores stay in flight).
// ---------------------------------------------------------------------------
#define GSTEP(PR, PW, T)                                                              \
  {                                                                                   \
    /* prefetch next step's x-proj triple (consumed next iteration) */                \
    const _Float16* xnp = xq + (size_t)((T) + 1 < Tt ? (T) + 1 : (T)) * G3;           \
    _Float16 pz = xnp[0], pr = xnp[Hh], pn = xnp[2 * Hh];                             \
    /* A fragments: broadcast h chunks (same addr within 16-lane group) */            \
    f16x8 af[8];                                                                      \
    _Pragma("unroll") for (int ks = 0; ks < 8; ++ks) {                                \
      V16 t;                                                                          \
      t.u = *reinterpret_cast<const uint4*>(                                          \
          reinterpret_cast<const char*>(&hs[PR][0]) + ks * 64 + kg * 16);             \
      af[ks] = t.f;                                                                   \
    }                                                                                 \
    /* streamed B fragments for K-steps 6,7 */                                        \
    f16x8 sb[3][2][2];                                                                \
    _Pragma("unroll") for (int g = 0; g < 3; ++g)                                     \
      _Pragma("unroll") for (int sub = 0; sub < 2; ++sub)                             \
        _Pragma("unroll") for (int ksl = 0; ksl < 2; ++ksl) {                         \
          const int n = g * Hh + C0 + sub * 16 + col16;                               \
          V16 t;                                                                      \
          t.u = *reinterpret_cast<const uint4*>(                                      \
              reinterpret_cast<const char*>(wlds) + (ksl * 768 + n) * 80 + kg * 16);  \
          sb[g][sub][ksl] = t.f;                                                      \
        }                                                                             \
    f32x4 acc[3][2];                                                                  \
    _Pragma("unroll") for (int g = 0; g < 3; ++g)                                     \
      _Pragma("unroll") for (int sub = 0; sub < 2; ++sub)                             \
        acc[g][sub] = (f32x4){0.f, 0.f, 0.f, 0.f};                                    \
    _Pragma("unroll") for (int ks = 0; ks < 6; ++ks)                                  \
      _Pragma("unroll") for (int g = 0; g < 3; ++g)                                   \
        _Pragma("unroll") for (int sub = 0; sub < 2; ++sub)                           \
          acc[g][sub] = __builtin_amdgcn_mfma_f32_16x16x32_f16(                       \
              af[ks], bfr[g][sub][ks], acc[g][sub], 0, 0, 0);                         \
    _Pragma("unroll") for (int ksl = 0; ksl < 2; ++ksl)                               \
      _Pragma("unroll") for (int g = 0; g < 3; ++g)                                   \
        _Pragma("unroll") for (int sub = 0; sub < 2; ++sub)                           \
          acc[g][sub] = __builtin_amdgcn_mfma_f32_16x16x32_f16(                       \
              af[6 + ksl], sb[g][sub][ksl], acc[g][sub], 0, 0, 0);                    \
    /* gates: col = C0 + (lane&31); sub selected by lane bit 4 */                     \
    float hz = sel ? acc[0][1][0] : acc[0][0][0];                                     \
    float hr = sel ? acc[1][1][0] : acc[1][0][0];                                     \
    float hn = sel ? acc[2][1][0] : acc[2][0][0];                                     \
    float zg = sigmoidf_(xz + hz);                                                    \
    float rg = sigmoidf_(xr + hr);                                                    \
    float ng = tanhf_(xn + rg * hn);                                                  \
    float hnew = zg * hprev + (1.0f - zg) * ng;                                       \
    hprev = hnew;                                                                     \
    if (lane < 32) {                                                                  \
      hs[PW][C0 + lcol] = (_Float16)hnew;                                             \
      yb[(size_t)(T) * Hh] = hnew;                                                    \
    }                                                                                 \
    xz = (float)pz; xr = (float)pr; xn = (float)pn;                                   \
    __builtin_amdgcn_sched_barrier(0);                                                \
    asm volatile("s_waitcnt lgkmcnt(0)" ::: "memory");                                \
    __builtin_amdgcn_s_barrier();                                                     \
    __builtin_amdgcn_sched_barrier(0);                                                \
  }

__global__ __launch_bounds__(512, 2)
void gru_scan_kernel(const _Float16* __restrict__ xp, const float* __restrict__ Wh,
                     float* __restrict__ y) {
    // streamed weights: K-steps 6,7 (k = 192..255), layout [ksl][col n][40 f16]
    __shared__ __align__(16) _Float16 wlds[2 * 768 * 40];
    __shared__ __align__(16) _Float16 hs[2][256];

    const int tid = threadIdx.x;
    const int b = blockIdx.x;
    const int wave = tid >> 6, lane = tid & 63;
    const int col16 = lane & 15, kg = lane >> 4;
    const int sel = (lane >> 4) & 1;  // sub-tile select for this lane's col
    const int lcol = lane & 31;
    const int C0 = 32 * wave;

    // register-resident B fragments: gates x sub x K-steps 0..5
    f16x8 bfr[3][2][6];
#pragma unroll
    for (int g = 0; g < 3; ++g)
#pragma unroll
        for (int sub = 0; sub < 2; ++sub)
#pragma unroll
            for (int ks = 0; ks < 6; ++ks) {
                V16 t;
#pragma unroll
                for (int j = 0; j < 8; ++j) {
                    const int k = 32 * ks + 8 * kg + j;
                    t.f[j] = (_Float16)Wh[(size_t)k * G3 + g * Hh + C0 + sub * 16 + col16];
                }
                bfr[g][sub][ks] = t.f;
            }

    // stage K-steps 6,7 into LDS (coalesced fp32 row reads, f16x2-packed writes)
    for (int kp = 0; kp < 32; ++kp) {
        const int k = 192 + 2 * kp;
        const int ksl = (k >> 5) - 6;
        const int koff = k & 31;
        for (int n = tid; n < 768; n += 512) {
            float f0 = Wh[(size_t)k * G3 + n];
            float f1 = Wh[(size_t)(k + 1) * G3 + n];
            H2U u; u.h[0] = (_Float16)f0; u.h[1] = (_Float16)f1;
            *reinterpret_cast<unsigned*>(
                reinterpret_cast<char*>(wlds) + (ksl * 768 + n) * 80 + koff * 2) = u.u;
        }
    }

    if (tid < 256) { hs[0][tid] = (_Float16)0.f; hs[1][tid] = (_Float16)0.f; }

    const _Float16* xq = xp + (size_t)b * Tt * G3 + C0 + lcol;
    float* yb = y + (size_t)b * Tt * Hh + C0 + lcol;
    float xz = (float)xq[0], xr = (float)xq[Hh], xn = (float)xq[2 * Hh];
    float hprev = 0.0f;

    __syncthreads();  // one-time full barrier (drains staging too)

#pragma unroll 1
    for (int t = 0; t < Tt; t += 2) {
        GSTEP(0, 1, t);
        GSTEP(1, 0, t + 1);
    }
}

extern "C" void kernel_launch(void* const* d_in, const int* in_sizes, int n_in,
                              void* d_out, int out_size, void* d_ws, size_t ws_size,
                              hipStream_t stream) {
    (void)in_sizes; (void)n_in; (void)out_size; (void)ws_size;
    const float* x    = (const float*)d_in[0];
    const float* Wx   = (const float*)d_in[1];
    const float* Wh   = (const float*)d_in[2];
    const float* bias = (const float*)d_in[3];
    float* y = (float*)d_out;

    _Float16* xp   = (_Float16*)d_ws;                                // 96 MB
    _Float16* xf16 = (_Float16*)d_out;                               // 33.5 MB scratch in d_out
    _Float16* wxt  = (_Float16*)((char*)d_out + (size_t)33554432);   // 384 KB, after xf16

    cvt_x_kernel<<<dim3(16384), dim3(256), 0, stream>>>(x, xf16);
    wxt_kernel<<<dim3(384), dim3(256), 0, stream>>>(Wx, wxt);
    gemm_xp_kernel<<<dim3(6144), dim3(256), 0, stream>>>(xf16, wxt, bias, xp);
    // scan reads only ws, writes all of d_out (overwriting the scratch regions)
    gru_scan_kernel<<<dim3(Bb), dim3(512), 0, stream>>>(xp, Wh, y);
}

// Round 4
// 2189.951 us; speedup vs baseline: 2.6719x; 1.0051x over previous
//
#include <hip/hip_runtime.h>

#define Bb 32
#define Tt 2048
#define Dd 256
#define Hh 256
#define G3 768  // 3*H

typedef _Float16 h2_t __attribute__((ext_vector_type(2)));
typedef _Float16 f16x8 __attribute__((ext_vector_type(8)));
typedef float f32x4 __attribute__((ext_vector_type(4)));
union H2U { unsigned u; _Float16 h[2]; h2_t v; };
union V16 { uint4 u; f16x8 f; };

__device__ __forceinline__ float fdot2f(unsigned a, unsigned b, float c) {
#if __has_builtin(__builtin_amdgcn_fdot2)
    H2U ua, ub; ua.u = a; ub.u = b;
    return __builtin_amdgcn_fdot2(ua.v, ub.v, c, false);
#else
    H2U ua, ub; ua.u = a; ub.u = b;
    return c + (float)ua.h[0] * (float)ub.h[0] + (float)ua.h[1] * (float)ub.h[1];
#endif
}

__device__ __forceinline__ float frcpf(float x) {
#if __has_builtin(__builtin_amdgcn_rcpf)
    return __builtin_amdgcn_rcpf(x);
#else
    return 1.0f / x;
#endif
}
__device__ __forceinline__ float sigmoidf_(float s) { return frcpf(1.0f + __expf(-s)); }
__device__ __forceinline__ float tanhf_(float u) {
    float e = __expf(2.0f * u);
    return 1.0f - 2.0f * frcpf(e + 1.0f);
}
// scalar-in/scalar-out DPP helpers (never pass arrays -- R2 lesson)
__device__ __forceinline__ float dpp_xor1(float v) {
    return __int_as_float(__builtin_amdgcn_update_dpp(0, __float_as_int(v), 0xB1, 0xF, 0xF, true));
}
__device__ __forceinline__ float dpp_xor2(float v) {
    return __int_as_float(__builtin_amdgcn_update_dpp(0, __float_as_int(v), 0x4E, 0xF, 0xF, true));
}

// ---------------------------------------------------------------------------
// k0: x fp32 -> f16 (into d_out scratch region)
// ---------------------------------------------------------------------------
__global__ void cvt_x_kernel(const float* __restrict__ x, _Float16* __restrict__ xo) {
    const size_t i = ((size_t)blockIdx.x * 256 + threadIdx.x) * 4;
    float4 v = *reinterpret_cast<const float4*>(x + i);
    H2U a, b;
    a.h[0] = (_Float16)v.x; a.h[1] = (_Float16)v.y;
    b.h[0] = (_Float16)v.z; b.h[1] = (_Float16)v.w;
    uint2 o; o.x = a.u; o.y = b.u;
    *reinterpret_cast<uint2*>(xo + i) = o;
}

// ---------------------------------------------------------------------------
// k1: WxT[n][k] f16 from Wx[k][n] fp32  (768 x 256)
// ---------------------------------------------------------------------------
__global__ void wxt_kernel(const float* __restrict__ Wx, _Float16* __restrict__ wxt) {
    const int o = blockIdx.x * 256 + threadIdx.x;  // o = n*128 + kp
    const int n = o >> 7, kp = o & 127;
    float f0 = Wx[(size_t)(2 * kp) * G3 + n];
    float f1 = Wx[(size_t)(2 * kp + 1) * G3 + n];
    H2U u; u.h[0] = (_Float16)f0; u.h[1] = (_Float16)f1;
    reinterpret_cast<unsigned*>(wxt)[o] = u.u;
}

// ---------------------------------------------------------------------------
// k2: xp = A(65536x256,f16) @ WxT^T + bias, f16 out. MFMA 16x16x32_f16.
// (unchanged -- ref-checked, k0..k2 combined ~71 us)
// ---------------------------------------------------------------------------
__global__ __launch_bounds__(256)
void gemm_xp_kernel(const _Float16* __restrict__ A, const _Float16* __restrict__ Bm,
                    const float* __restrict__ bias, _Float16* __restrict__ xp) {
    __shared__ _Float16 As[128][264];
    __shared__ _Float16 Bs[64][264];
    const int tid = threadIdx.x;
    const int m0 = (blockIdx.x / 12) * 128;
    const int n0 = (blockIdx.x % 12) * 64;

#pragma unroll
    for (int it = 0; it < 16; ++it) {
        int c = tid + it * 256, row = c >> 5, col = c & 31;
        uint4 v = *reinterpret_cast<const uint4*>(A + (size_t)(m0 + row) * 256 + col * 8);
        *reinterpret_cast<uint4*>(&As[row][col * 8]) = v;
    }
#pragma unroll
    for (int it = 0; it < 8; ++it) {
        int c = tid + it * 256, row = c >> 5, col = c & 31;
        uint4 v = *reinterpret_cast<const uint4*>(Bm + (size_t)(n0 + row) * 256 + col * 8);
        *reinterpret_cast<uint4*>(&Bs[row][col * 8]) = v;
    }
    __syncthreads();

    const int wave = tid >> 6, lane = tid & 63;
    const int wr = wave >> 1, wc = wave & 1;
    const int r16 = lane & 15, kg = lane >> 4;

    f32x4 acc[4][2];
#pragma unroll
    for (int mi = 0; mi < 4; ++mi)
#pragma unroll
        for (int ni = 0; ni < 2; ++ni) acc[mi][ni] = (f32x4){0.f, 0.f, 0.f, 0.f};

    float bv[2];
#pragma unroll
    for (int ni = 0; ni < 2; ++ni) bv[ni] = bias[n0 + wc * 32 + ni * 16 + r16];

#pragma unroll
    for (int kk = 0; kk < 8; ++kk) {
        f16x8 a[4], b2[2];
#pragma unroll
        for (int mi = 0; mi < 4; ++mi) {
            V16 t; t.u = *reinterpret_cast<const uint4*>(&As[wr * 64 + mi * 16 + r16][kk * 32 + kg * 8]);
            a[mi] = t.f;
        }
#pragma unroll
        for (int ni = 0; ni < 2; ++ni) {
            V16 t; t.u = *reinterpret_cast<const uint4*>(&Bs[wc * 32 + ni * 16 + r16][kk * 32 + kg * 8]);
            b2[ni] = t.f;
        }
#pragma unroll
        for (int mi = 0; mi < 4; ++mi)
#pragma unroll
            for (int ni = 0; ni < 2; ++ni)
                acc[mi][ni] = __builtin_amdgcn_mfma_f32_16x16x32_f16(a[mi], b2[ni], acc[mi][ni], 0, 0, 0);
    }

#pragma unroll
    for (int mi = 0; mi < 4; ++mi)
#pragma unroll
        for (int ni = 0; ni < 2; ++ni)
#pragma unroll
            for (int r = 0; r < 4; ++r) {
                int row = m0 + wr * 64 + mi * 16 + kg * 4 + r;
                int col = n0 + wc * 32 + ni * 16 + r16;
                xp[(size_t)row * G3 + col] = (_Float16)(acc[mi][ni][r] + bv[ni]);
            }
}

// ---------------------------------------------------------------------------
// k3: GRU scan, pure VALU v_dot2_f32_f16 (no MFMA: M=1 broadcast wastes 16x
// of the matrix pipe -- VALU dot2 floor is 768 cyc/SIMD/step vs MFMA 1863).
// 32 blocks (1/batch) x 512 threads (8 waves, 2/SIMD).
// Thread (slot=tid>>2, q=tid&3): owns h-cols {2*slot, 2*slot+1} for all 3
// gates, over k-chunk [64q, 64q+64). Weights = 192 u32 (f16x2) per thread,
// ALL statically indexed, nothing passed by pointer (R2 escape lesson).
// Cross-q reduction = 2 DPP quad_perm stages (quads == q groups).
// h in LDS as 4 chunks of 32 u32, chunk stride 36 u32 (16B pad) so the four
// q-group broadcast b128 reads hit disjoint bank-quads.
// ---------------------------------------------------------------------------
#define GDOT(HF)                                                                      \
  {                                                                                   \
    uint4 h0 = hq[(HF) * 2 + 0];                                                      \
    uint4 h1 = hq[(HF) * 2 + 1];                                                      \
    _Pragma("unroll") for (int u = 0; u < 4; ++u) {                                   \
      const unsigned hu = (u == 0) ? h0.x : (u == 1) ? h0.y : (u == 2) ? h0.z : h0.w; \
      sz0 = fdot2f(w[0][0][(HF) * 8 + u], hu, sz0);                                   \
      sr0 = fdot2f(w[1][0][(HF) * 8 + u], hu, sr0);                                   \
      sn0 = fdot2f(w[2][0][(HF) * 8 + u], hu, sn0);                                   \
      sz1 = fdot2f(w[0][1][(HF) * 8 + u], hu, sz1);                                   \
      sr1 = fdot2f(w[1][1][(HF) * 8 + u], hu, sr1);                                   \
      sn1 = fdot2f(w[2][1][(HF) * 8 + u], hu, sn1);                                   \
    }                                                                                 \
    _Pragma("unroll") for (int u = 0; u < 4; ++u) {                                   \
      const unsigned hu = (u == 0) ? h1.x : (u == 1) ? h1.y : (u == 2) ? h1.z : h1.w; \
      sz0 = fdot2f(w[0][0][(HF) * 8 + 4 + u], hu, sz0);                               \
      sr0 = fdot2f(w[1][0][(HF) * 8 + 4 + u], hu, sr0);                               \
      sn0 = fdot2f(w[2][0][(HF) * 8 + 4 + u], hu, sn0);                               \
      sz1 = fdot2f(w[0][1][(HF) * 8 + 4 + u], hu, sz1);                               \
      sr1 = fdot2f(w[1][1][(HF) * 8 + 4 + u], hu, sr1);                               \
      sn1 = fdot2f(w[2][1][(HF) * 8 + 4 + u], hu, sn1);                               \
    }                                                                                 \
  }

#define GSTEP(PR, PW, T)                                                              \
  {                                                                                   \
    /* prefetch next step's x-proj triple (used next iteration; vmcnt not */          \
    /* drained at the barrier, compiler waits only before first use) */               \
    const _Float16* xnp = xq + (size_t)((T) + 1 < Tt ? (T) + 1 : (T)) * G3;           \
    _Float16 pz = xnp[0], pr = xnp[Hh], pn = xnp[2 * Hh];                             \
    float sz0 = 0.f, sz1 = 0.f, sr0 = 0.f, sr1 = 0.f, sn0 = 0.f, sn1 = 0.f;           \
    const uint4* hq = reinterpret_cast<const uint4*>(&hbuf[PR][q * 36]);              \
    GDOT(0) GDOT(1) GDOT(2) GDOT(3)                                                   \
    /* quad butterfly: all 4 lanes end with full-k sums */                            \
    sz0 += dpp_xor1(sz0); sz1 += dpp_xor1(sz1);                                       \
    sr0 += dpp_xor1(sr0); sr1 += dpp_xor1(sr1);                                       \
    sn0 += dpp_xor1(sn0); sn1 += dpp_xor1(sn1);                                       \
    sz0 += dpp_xor2(sz0); sz1 += dpp_xor2(sz1);                                       \
    sr0 += dpp_xor2(sr0); sr1 += dpp_xor2(sr1);                                       \
    sn0 += dpp_xor2(sn0); sn1 += dpp_xor2(sn1);                                       \
    const float hz = (q & 1) ? sz1 : sz0;                                             \
    const float hr = (q & 1) ? sr1 : sr0;                                             \
    const float hn = (q & 1) ? sn1 : sn0;                                             \
    const float zg = sigmoidf_(xz + hz);                                              \
    const float rg = sigmoidf_(xr + hr);                                              \
    const float ng = tanhf_(xn + rg * hn);                                            \
    const float hnew = zg * hprev + (1.0f - zg) * ng;                                 \
    hprev = hnew;                                                                     \
    H2U hc; hc.h[0] = (_Float16)hnew; hc.h[1] = (_Float16)0.f;                        \
    const unsigned pu = (unsigned)__builtin_amdgcn_update_dpp(0, (int)hc.u, 0xB1, 0xF, 0xF, true); \
    const int pf = __builtin_amdgcn_update_dpp(0, __float_as_int(hnew), 0xB1, 0xF, 0xF, true);      \
    if (q == 0) {                                                                     \
      hbuf[PW][(slot >> 5) * 36 + (slot & 31)] = (hc.u & 0xFFFFu) | (pu << 16);       \
      float2 yv; yv.x = hnew; yv.y = __int_as_float(pf);                              \
      *reinterpret_cast<float2*>(yb + (size_t)(T) * Hh) = yv;                         \
    }                                                                                 \
    xz = (float)pz; xr = (float)pr; xn = (float)pn;                                   \
    __builtin_amdgcn_sched_barrier(0);                                                \
    asm volatile("s_waitcnt lgkmcnt(0)" ::: "memory");                                \
    __builtin_amdgcn_s_barrier();                                                     \
    __builtin_amdgcn_sched_barrier(0);                                                \
  }

__global__ __launch_bounds__(512, 2)
void gru_scan_kernel(const _Float16* __restrict__ xp, const float* __restrict__ Wh,
                     float* __restrict__ y) {
    __shared__ unsigned hbuf[2][144];  // 4 chunks x (32 u32 + 4 pad)

    const int tid = threadIdx.x;
    const int b = blockIdx.x;
    const int q = tid & 3;       // k-split quadrant: k in [64q, 64q+64)
    const int slot = tid >> 2;   // [0,128): owns h-cols 2*slot, 2*slot+1

    // weights: [gate][col 0/1][32 k-pairs] packed f16x2 -- 192 u32, all
    // indices compile-time constants after unroll (must stay in VGPRs)
    unsigned w[3][2][32];
#pragma unroll
    for (int g = 0; g < 3; ++g) {
        const int c0 = g * Hh + 2 * slot;
#pragma unroll
        for (int kp = 0; kp < 32; ++kp) {
            const int k = 64 * q + 2 * kp;
            float2 f0 = *reinterpret_cast<const float2*>(Wh + (size_t)k * G3 + c0);
            float2 f1 = *reinterpret_cast<const float2*>(Wh + (size_t)(k + 1) * G3 + c0);
            H2U p0, p1;
            p0.h[0] = (_Float16)f0.x; p0.h[1] = (_Float16)f1.x;
            p1.h[0] = (_Float16)f0.y; p1.h[1] = (_Float16)f1.y;
            w[g][0][kp] = p0.u;
            w[g][1][kp] = p1.u;
        }
    }

    if (tid < 288) hbuf[tid / 144][tid % 144] = 0u;  // h0 = 0 (both buffers)
    float hprev = 0.0f;

    const int j = 2 * slot + (q & 1);  // gate lane's h-col (valid for q<2)
    const _Float16* xq = xp + (size_t)b * Tt * G3 + j;
    float* yb = y + (size_t)b * Tt * Hh + 2 * slot;  // float2 store by q==0
    float xz = (float)xq[0], xr = (float)xq[Hh], xn = (float)xq[2 * Hh];

    __syncthreads();  // one-time full barrier (drains weight loads too)

#pragma unroll 1
    for (int t = 0; t < Tt; t += 2) {
        GSTEP(0, 1, t);
        GSTEP(1, 0, t + 1);
    }
}

extern "C" void kernel_launch(void* const* d_in, const int* in_sizes, int n_in,
                              void* d_out, int out_size, void* d_ws, size_t ws_size,
                              hipStream_t stream) {
    (void)in_sizes; (void)n_in; (void)out_size; (void)ws_size;
    const float* x    = (const float*)d_in[0];
    const float* Wx   = (const float*)d_in[1];
    const float* Wh   = (const float*)d_in[2];
    const float* bias = (const float*)d_in[3];
    float* y = (float*)d_out;

    _Float16* xp   = (_Float16*)d_ws;                                // 96 MB
    _Float16* xf16 = (_Float16*)d_out;                               // 33.5 MB scratch in d_out
    _Float16* wxt  = (_Float16*)((char*)d_out + (size_t)33554432);   // 384 KB, after xf16

    cvt_x_kernel<<<dim3(16384), dim3(256), 0, stream>>>(x, xf16);
    wxt_kernel<<<dim3(384), dim3(256), 0, stream>>>(Wx, wxt);
    gemm_xp_kernel<<<dim3(6144), dim3(256), 0, stream>>>(xf16, wxt, bias, xp);
    // scan reads only ws, writes all of d_out (overwriting the scratch regions)
    gru_scan_kernel<<<dim3(Bb), dim3(512), 0, stream>>>(xp, Wh, y);
}